// Round 14
// baseline (161.371 us; speedup 1.0000x reference)
//
#include <hip/hip_runtime.h>

#define HW   (256*256)        // 65536
#define VOL  (64*HW)          // 4194304 per batch volume
#define NTOT (4ull*VOL)
#define C1v  1e-4f
#define C2v  9e-4f
#define EPSv 1e-8f

typedef float    f2 __attribute__((ext_vector_type(2)));
typedef float    f4 __attribute__((ext_vector_type(4)));
typedef _Float16 h2 __attribute__((ext_vector_type(2)));
typedef _Float16 h4 __attribute__((ext_vector_type(4)));
typedef _Float16 h8 __attribute__((ext_vector_type(8)));

// ws layout:
// [0      .. 63]     : w[11] float (1D separable weights)
// [64     .. 16447]  : partials[2048] double
// [16640  .. ]       : packed field volumes, 10 bytes/element per batch:
//                      FA = h4{X,Y,XX,YY}[VOL] (8 B/elem), F2 = f16 XY[VOL] (2 B/elem)

__global__ void init_weights(const float* __restrict__ k3, float* __restrict__ w) {
    int i = threadIdx.x;
    if (i < 11) {
        float s = 0.f;
        for (int t = 0; t < 121; ++t) s += k3[i * 121 + t];
        w[i] = s;   // k3 is separable: row-sum = 1D weight
    }
}

// Pass 1 via MFMA banded matmuls — r13 structure + 26-row staging + fused h4 stores.
//   PB[5][32][88] rows 176 B (2-way free); rows 26..31 zero-filled once (A mc=1 pad)
//   TT[5][64][32] aliases PB, cols 64 B, swizzle byte ^= (col&7)<<4 (wave-private)
//   WB/AH[16][40] rows 80 B
//   barriers: 2 (stage->Wconv reads; Wconv reads->TT writes)
// grid: (4, 16, 64*nb) x 256.
__global__ __launch_bounds__(256) void blur_hw(
    const float* __restrict__ x, const float* __restrict__ y,
    const float* __restrict__ w11, char* __restrict__ fields, int b0)
{
    __shared__ alignas(16) _Float16 PB[5 * 32 * 88];  // 28,160 B; TT (20,480 B) aliases
    __shared__ alignas(16) _Float16 WB[16][40];       //  1,280 B
    __shared__ alignas(16) _Float16 AH[16][40];       //  1,280 B -> 30,720 B (5 blk/CU)

    const int d   = blockIdx.z & 63;
    const int bz  = blockIdx.z >> 6;
    const int h0  = blockIdx.y * 16;
    const int w0  = blockIdx.x * 64;
    const int tid = threadIdx.x;

    // ---- band tables: 512 items (cols 32..39 pad, never read) ----
#pragma unroll
    for (int it = 0; it < 2; ++it) {
        int t = tid + it * 256;
        int n = t >> 5, k = t & 31;
        int i1 = k - n - 1;                 // W band (staged-col shift)
        int i2 = k - n;                     // H band
        float v1 = ((unsigned)i1 <= 10u) ? w11[min(max(i1, 0), 10)] : 0.f;
        float v2 = ((unsigned)i2 <= 10u) ? w11[min(max(i2, 0), 10)] : 0.f;
        WB[n][k] = (_Float16)v1;
        AH[n][k] = (_Float16)v2;
    }

    const float* xb = x + (size_t)(b0 + bz) * VOL + (size_t)d * HW;
    const float* yb = y + (size_t)(b0 + bz) * VOL + (size_t)d * HW;

    // ---- stage products: 26 rows x 40 col-pairs = 1040 items (weighted rows only),
    //      branchless clamped loads inside, wave-mostly-uniform guard outside ----
#pragma unroll
    for (int it = 0; it < 5; ++it) {
        int p = tid + it * 256;
        if (p < 1040) {
            int r = p / 40, j = p - r * 40;
            int gh = h0 - 5 + r;
            int gw = w0 - 6 + 2 * j;            // even
            bool ok = ((unsigned)gh < 256u) & ((unsigned)gw < 256u);
            int idx = min(max(gh, 0), 255) * 256 + min(max(gw, 0), 254);
            f2 xv = *(const f2*)&xb[idx];
            f2 yv = *(const f2*)&yb[idx];
            if (!ok) { xv = (f2){0.f, 0.f}; yv = (f2){0.f, 0.f}; }
            _Float16* pb = PB + r * 88 + j * 2;          // field stride 2816 halves
            *(h2*)(pb + 0)     = (h2){(_Float16)xv[0], (_Float16)xv[1]};
            *(h2*)(pb + 2816)  = (h2){(_Float16)yv[0], (_Float16)yv[1]};
            *(h2*)(pb + 5632)  = (h2){(_Float16)(xv[0]*xv[0]), (_Float16)(xv[1]*xv[1])};
            *(h2*)(pb + 8448)  = (h2){(_Float16)(yv[0]*yv[0]), (_Float16)(yv[1]*yv[1])};
            *(h2*)(pb + 11264) = (h2){(_Float16)(xv[0]*yv[0]), (_Float16)(xv[1]*yv[1])};
        }
    }
    // ---- zero-fill rows 26..31 (read as A-frag mc=1 rows; must be finite) ----
    {
        int p = tid;                         // 240 items = 6 rows x 40 pairs
        if (p < 240) {
            int r = 26 + p / 40, j = p - (p / 40) * 40;
            _Float16* pb = PB + r * 88 + j * 2;
            h2 z = (h2){(_Float16)0.f, (_Float16)0.f};
            *(h2*)(pb + 0)     = z;
            *(h2*)(pb + 2816)  = z;
            *(h2*)(pb + 5632)  = z;
            *(h2*)(pb + 8448)  = z;
            *(h2*)(pb + 11264) = z;
        }
    }
    __syncthreads();   // barrier 1: staging -> W-conv reads

    const int lane = tid & 63, wid = tid >> 6;
    const int lm = lane & 15, lk = lane >> 4;
    const int col = wid * 16 + lm;                     // 0..63, wave-private block
    const int tswz = (col & 7) << 4;                   // bits 4,5 inner; bit 6 = col b0

    // ---- W-conv into registers (PB still live) ----
    h4 wres[10];
    {
        h8 bw = *(const h8*)((const char*)WB + lm * 80 + lk * 16);
        const char* Ab = (const char*)PB + lm * 176 + wid * 32 + lk * 16;
#pragma unroll
        for (int f = 0; f < 5; ++f) {
#pragma unroll
            for (int mc = 0; mc < 2; ++mc) {
                h8 a = *(const h8*)(Ab + f * 5632 + mc * 2816);
                f4 dv = __builtin_amdgcn_mfma_f32_16x16x32_f16(
                            a, bw, (f4){0.f, 0.f, 0.f, 0.f}, 0, 0, 0);
                wres[f * 2 + mc] = (h4){(_Float16)dv[0], (_Float16)dv[1],
                                        (_Float16)dv[2], (_Float16)dv[3]};
            }
        }
    }
    __syncthreads();   // barrier 2: all PB reads done -> safe to overwrite with TT

    // ---- write swizzled TT (aliased over PB); cols wave-private ----
    {
        char* T0 = (char*)PB;
#pragma unroll
        for (int f = 0; f < 5; ++f) {
#pragma unroll
            for (int mc = 0; mc < 2; ++mc) {
                char* dst = T0 + ((col * 64 + mc * 32 + lk * 8) ^ tswz) + f * 4096;
                *(h4*)dst = wres[f * 2 + mc];
            }
        }
    }
    // no barrier: wave reads exactly the TT cols it wrote (lgkmcnt ordered)

    // ---- H-conv: wave = N-chunk; 5 fields, fused h4 + h2 stores ----
    {
        h8 ah = *(const h8*)((const char*)AH + lm * 80 + lk * 16);
        const char* Tb = (const char*)PB + ((col * 64 + lk * 16) ^ tswz);
        f4 d0 = __builtin_amdgcn_mfma_f32_16x16x32_f16(ah, *(const h8*)(Tb + 0),
                    (f4){0.f,0.f,0.f,0.f}, 0, 0, 0);
        f4 d1 = __builtin_amdgcn_mfma_f32_16x16x32_f16(ah, *(const h8*)(Tb + 4096),
                    (f4){0.f,0.f,0.f,0.f}, 0, 0, 0);
        f4 d2 = __builtin_amdgcn_mfma_f32_16x16x32_f16(ah, *(const h8*)(Tb + 8192),
                    (f4){0.f,0.f,0.f,0.f}, 0, 0, 0);
        f4 d3 = __builtin_amdgcn_mfma_f32_16x16x32_f16(ah, *(const h8*)(Tb + 12288),
                    (f4){0.f,0.f,0.f,0.f}, 0, 0, 0);
        f4 d4 = __builtin_amdgcn_mfma_f32_16x16x32_f16(ah, *(const h8*)(Tb + 16384),
                    (f4){0.f,0.f,0.f,0.f}, 0, 0, 0);

        h4* FA = (h4*)(fields + (size_t)bz * 10 * VOL);
        _Float16* F2 = (_Float16*)((char*)FA + (size_t)8 * VOL);

        const int gcol = w0 + col;
#pragma unroll
        for (int rg = 0; rg < 4; ++rg) {
            int row = lk * 4 + rg;
            size_t oi = (size_t)d * HW + (size_t)(h0 + row) * 256 + gcol;
            FA[oi] = (h4){(_Float16)d0[rg], (_Float16)d1[rg],
                          (_Float16)d2[rg], (_Float16)d3[rg]};
            F2[oi] = (_Float16)d4[rg];
        }
    }
}

// Pass 2: D-conv via scalar fp32 register rings, fused h4 field loads.
// DHALF compile-time so ALL guards fold; grid: (256, nb) x 256.
template<int DHALF>
__global__ __launch_bounds__(256) void dconv_ssim(
    const char* __restrict__ fields, const float* __restrict__ w11,
    double* __restrict__ partials, int b0)
{
    const int col = blockIdx.x * 256 + threadIdx.x;  // 0..65535 within slice
    const int bz  = blockIdx.y;

    float wl[11];
#pragma unroll
    for (int t = 0; t < 11; ++t) wl[t] = w11[t];

    const h4* FA = (const h4*)(fields + (size_t)bz * 10 * VOL);
    const _Float16* F2 = (const _Float16*)((const char*)FA + (size_t)8 * VOL);

    float bX[11], bY[11], bXX[11], bYY[11], bXY[11];
#pragma unroll
    for (int t = 0; t < 11; ++t) { bX[t] = 0; bY[t] = 0; bXX[t] = 0; bYY[t] = 0; bXY[t] = 0; }

    float acc = 0.f;
#pragma unroll
    for (int s = 0; s < 42; ++s) {
        const int dd = DHALF * 32 - 5 + s;          // compile-time after unroll
        const int slot = s % 11;                    // compile-time
        if (dd >= 0 && dd < 64) {                   // compile-time
            size_t idx = (size_t)dd * HW + col;
            h4 v = FA[idx];
            _Float16 vxy = F2[idx];
            bX[slot]  = (float)v[0];
            bY[slot]  = (float)v[1];
            bXX[slot] = (float)v[2];
            bYY[slot] = (float)v[3];
            bXY[slot] = (float)vxy;
        } else {
            bX[slot] = 0; bY[slot] = 0; bXX[slot] = 0; bYY[slot] = 0; bXY[slot] = 0;
        }

        if (s >= 10) {                              // compile-time; emit depth DHALF*32 + s-10
            float mX = 0, mY = 0, cXX = 0, cYY = 0, cXY = 0;
#pragma unroll
            for (int t = 0; t < 11; ++t) {
                const int j = (s + 1 + t) % 11;     // compile-time
                float wt = wl[t];
                mX  += wt * bX[j];
                mY  += wt * bY[j];
                cXX += wt * bXX[j];
                cYY += wt * bYY[j];
                cXY += wt * bXY[j];
            }
            float mx2 = mX * mX, my2 = mY * mY, mxy = mX * mY;
            float sx2 = cXX - mx2, sy2 = cYY - my2, sxy = cXY - mxy;
            float num = (2.f * mxy + C1v) * (2.f * sxy + C2v);
            float den = (mx2 + my2 + C1v) * (sx2 + sy2 + C2v);
            acc += num * __builtin_amdgcn_rcpf(den + EPSv);
        }
    }

    // reduce 256 threads -> one partial per block (deterministic)
    for (int off = 32; off; off >>= 1) acc += __shfl_down(acc, off, 64);
    __shared__ float wsum[4];
    int lane = threadIdx.x & 63, wid = threadIdx.x >> 6;
    if (lane == 0) wsum[wid] = acc;
    __syncthreads();
    if (threadIdx.x == 0) {
        float s = wsum[0] + wsum[1] + wsum[2] + wsum[3];
        partials[(size_t)(b0 + bz) * 512 + DHALF * 256 + blockIdx.x] = (double)s;
    }
}

__global__ void finalize(const double* __restrict__ partials, float* __restrict__ out, int n) {
    __shared__ double sh[256];
    double s = 0.0;
    for (int i = threadIdx.x; i < n; i += 256) s += partials[i];
    sh[threadIdx.x] = s;
    __syncthreads();
    for (int stride = 128; stride; stride >>= 1) {
        if (threadIdx.x < stride) sh[threadIdx.x] += sh[threadIdx.x + stride];
        __syncthreads();
    }
    if (threadIdx.x == 0) out[0] = 1.0f - (float)(sh[0] / (double)NTOT);
}

extern "C" void kernel_launch(void* const* d_in, const int* in_sizes, int n_in,
                              void* d_out, int out_size, void* d_ws, size_t ws_size,
                              hipStream_t stream) {
    const float* x  = (const float*)d_in[0];
    const float* y  = (const float*)d_in[1];
    const float* k3 = (const float*)d_in[2];
    float* out = (float*)d_out;

    char* ws = (char*)d_ws;
    float*   w11      = (float*)ws;
    double*  partials = (double*)(ws + 64);
    char*    fields   = ws + 16640;

    const size_t perBatch = (size_t)10 * VOL;   // packed fp16 fields per batch (bytes)
    const bool all4 = ws_size >= 16640 + 4 * perBatch;

    init_weights<<<1, 64, 0, stream>>>(k3, w11);

    if (all4) {
        blur_hw      <<<dim3(4, 16, 256), 256, 0, stream>>>(x, y, w11, fields, 0);
        dconv_ssim<0><<<dim3(256, 4),     256, 0, stream>>>(fields, w11, partials, 0);
        dconv_ssim<1><<<dim3(256, 4),     256, 0, stream>>>(fields, w11, partials, 0);
    } else {
        for (int b = 0; b < 4; ++b) {
            blur_hw      <<<dim3(4, 16, 64), 256, 0, stream>>>(x, y, w11, fields, b);
            dconv_ssim<0><<<dim3(256, 1),    256, 0, stream>>>(fields, w11, partials, b);
            dconv_ssim<1><<<dim3(256, 1),    256, 0, stream>>>(fields, w11, partials, b);
        }
    }

    finalize<<<1, 256, 0, stream>>>(partials, out, 2048);
}

// Round 15
// 145.819 us; speedup vs baseline: 1.1067x; 1.1067x over previous
//
#include <hip/hip_runtime.h>

#define HW   (256*256)        // 65536
#define VOL  (64*HW)          // 4194304 per batch volume
#define NTOT (4ull*VOL)
#define C1v  1e-4f
#define C2v  9e-4f
#define EPSv 1e-8f

typedef float    f2 __attribute__((ext_vector_type(2)));
typedef float    f4 __attribute__((ext_vector_type(4)));
typedef _Float16 h2 __attribute__((ext_vector_type(2)));
typedef _Float16 h4 __attribute__((ext_vector_type(4)));
typedef _Float16 h8 __attribute__((ext_vector_type(8)));

// ws layout:
// [0      .. 63]     : w[11] float (1D separable weights)
// [64     .. 16447]  : partials[2048] double
// [16640  .. ]       : packed field volumes, 10 bytes/element per batch:
//                      FA = h4{X,Y,XX,YY}[VOL] (8 B/elem), F2 = f16 XY[VOL] (2 B/elem)

__global__ void init_weights(const float* __restrict__ k3, float* __restrict__ w) {
    int i = threadIdx.x;
    if (i < 11) {
        float s = 0.f;
        for (int t = 0; t < 121; ++t) s += k3[i * 121 + t];
        w[i] = s;   // k3 is separable: row-sum = 1D weight
    }
}

// Pass 1 via MFMA banded matmuls — r13 blur body (branchless 32-row staging,
// 5 blk/CU alias structure) + r14 fused FA/F2 stores.
//   PB[5][32][88] rows 176 B (2-way free); TT[5][64][32] aliases PB, swizzle
//   byte ^= (col&7)<<4 (wave-private); WB/AH[16][40] rows 80 B.
//   barriers: 2 (stage->Wconv reads; Wconv reads->TT writes)
// grid: (4, 16, 64*nb) x 256.
__global__ __launch_bounds__(256) void blur_hw(
    const float* __restrict__ x, const float* __restrict__ y,
    const float* __restrict__ w11, char* __restrict__ fields, int b0)
{
    __shared__ alignas(16) _Float16 PB[5 * 32 * 88];  // 28,160 B; TT (20,480 B) aliases
    __shared__ alignas(16) _Float16 WB[16][40];       //  1,280 B
    __shared__ alignas(16) _Float16 AH[16][40];       //  1,280 B -> 30,720 B (5 blk/CU)

    const int d   = blockIdx.z & 63;
    const int bz  = blockIdx.z >> 6;
    const int h0  = blockIdx.y * 16;
    const int w0  = blockIdx.x * 64;
    const int tid = threadIdx.x;

    // ---- band tables: 512 items (cols 32..39 pad, never read) ----
#pragma unroll
    for (int it = 0; it < 2; ++it) {
        int t = tid + it * 256;
        int n = t >> 5, k = t & 31;
        int i1 = k - n - 1;                 // W band (staged-col shift)
        int i2 = k - n;                     // H band
        float v1 = ((unsigned)i1 <= 10u) ? w11[min(max(i1, 0), 10)] : 0.f;
        float v2 = ((unsigned)i2 <= 10u) ? w11[min(max(i2, 0), 10)] : 0.f;
        WB[n][k] = (_Float16)v1;
        AH[n][k] = (_Float16)v2;
    }

    const float* xb = x + (size_t)(b0 + bz) * VOL + (size_t)d * HW;
    const float* yb = y + (size_t)(b0 + bz) * VOL + (size_t)d * HW;

    // ---- stage products: 32 rows x 40 col-pairs = 1280 = 5*256 exact,
    //      branchless clamped loads, zero via cndmask (r13 proven form) ----
#pragma unroll
    for (int it = 0; it < 5; ++it) {
        int p = tid + it * 256;
        int r = p / 40, j = p - r * 40;
        int gh = h0 - 5 + r;
        int gw = w0 - 6 + 2 * j;            // even
        bool ok = (r < 26) & ((unsigned)gh < 256u) & ((unsigned)gw < 256u);
        int idx = min(max(gh, 0), 255) * 256 + min(max(gw, 0), 254);
        f2 xv = *(const f2*)&xb[idx];
        f2 yv = *(const f2*)&yb[idx];
        if (!ok) { xv = (f2){0.f, 0.f}; yv = (f2){0.f, 0.f}; }
        _Float16* pb = PB + r * 88 + j * 2;          // field stride 2816 halves
        *(h2*)(pb + 0)     = (h2){(_Float16)xv[0], (_Float16)xv[1]};
        *(h2*)(pb + 2816)  = (h2){(_Float16)yv[0], (_Float16)yv[1]};
        *(h2*)(pb + 5632)  = (h2){(_Float16)(xv[0]*xv[0]), (_Float16)(xv[1]*xv[1])};
        *(h2*)(pb + 8448)  = (h2){(_Float16)(yv[0]*yv[0]), (_Float16)(yv[1]*yv[1])};
        *(h2*)(pb + 11264) = (h2){(_Float16)(xv[0]*yv[0]), (_Float16)(xv[1]*yv[1])};
    }
    __syncthreads();   // barrier 1: staging -> W-conv reads

    const int lane = tid & 63, wid = tid >> 6;
    const int lm = lane & 15, lk = lane >> 4;
    const int col = wid * 16 + lm;                     // 0..63, wave-private block
    const int tswz = (col & 7) << 4;                   // bits 4,5 inner; bit 6 = col b0

    // ---- W-conv into registers (PB still live) ----
    h4 wres[10];
    {
        h8 bw = *(const h8*)((const char*)WB + lm * 80 + lk * 16);
        const char* Ab = (const char*)PB + lm * 176 + wid * 32 + lk * 16;
#pragma unroll
        for (int f = 0; f < 5; ++f) {
#pragma unroll
            for (int mc = 0; mc < 2; ++mc) {
                h8 a = *(const h8*)(Ab + f * 5632 + mc * 2816);
                f4 dv = __builtin_amdgcn_mfma_f32_16x16x32_f16(
                            a, bw, (f4){0.f, 0.f, 0.f, 0.f}, 0, 0, 0);
                wres[f * 2 + mc] = (h4){(_Float16)dv[0], (_Float16)dv[1],
                                        (_Float16)dv[2], (_Float16)dv[3]};
            }
        }
    }
    __syncthreads();   // barrier 2: all PB reads done -> safe to overwrite with TT

    // ---- write swizzled TT (aliased over PB); cols wave-private ----
    {
        char* T0 = (char*)PB;
#pragma unroll
        for (int f = 0; f < 5; ++f) {
#pragma unroll
            for (int mc = 0; mc < 2; ++mc) {
                char* dst = T0 + ((col * 64 + mc * 32 + lk * 8) ^ tswz) + f * 4096;
                *(h4*)dst = wres[f * 2 + mc];
            }
        }
    }
    // no barrier: wave reads exactly the TT cols it wrote (lgkmcnt ordered)

    // ---- H-conv: wave = N-chunk; 5 fields, fused FA(h4) + F2(h2-scalar) stores ----
    {
        h8 ah = *(const h8*)((const char*)AH + lm * 80 + lk * 16);
        const char* Tb = (const char*)PB + ((col * 64 + lk * 16) ^ tswz);
        f4 d0 = __builtin_amdgcn_mfma_f32_16x16x32_f16(ah, *(const h8*)(Tb + 0),
                    (f4){0.f,0.f,0.f,0.f}, 0, 0, 0);
        f4 d1 = __builtin_amdgcn_mfma_f32_16x16x32_f16(ah, *(const h8*)(Tb + 4096),
                    (f4){0.f,0.f,0.f,0.f}, 0, 0, 0);
        f4 d2 = __builtin_amdgcn_mfma_f32_16x16x32_f16(ah, *(const h8*)(Tb + 8192),
                    (f4){0.f,0.f,0.f,0.f}, 0, 0, 0);
        f4 d3 = __builtin_amdgcn_mfma_f32_16x16x32_f16(ah, *(const h8*)(Tb + 12288),
                    (f4){0.f,0.f,0.f,0.f}, 0, 0, 0);
        f4 d4 = __builtin_amdgcn_mfma_f32_16x16x32_f16(ah, *(const h8*)(Tb + 16384),
                    (f4){0.f,0.f,0.f,0.f}, 0, 0, 0);

        h4* FA = (h4*)(fields + (size_t)bz * 10 * VOL);
        _Float16* F2 = (_Float16*)((char*)FA + (size_t)8 * VOL);

        const int gcol = w0 + col;
#pragma unroll
        for (int rg = 0; rg < 4; ++rg) {
            int row = lk * 4 + rg;
            size_t oi = (size_t)d * HW + (size_t)(h0 + row) * 256 + gcol;
            FA[oi] = (h4){(_Float16)d0[rg], (_Float16)d1[rg],
                          (_Float16)d2[rg], (_Float16)d3[rg]};
            F2[oi] = (_Float16)d4[rg];
        }
    }
}

// Pass 2: D-conv via scalar fp32 register rings, fused h4 field loads.
// DHALF compile-time so ALL guards fold; grid: (256, nb) x 256.
template<int DHALF>
__global__ __launch_bounds__(256) void dconv_ssim(
    const char* __restrict__ fields, const float* __restrict__ w11,
    double* __restrict__ partials, int b0)
{
    const int col = blockIdx.x * 256 + threadIdx.x;  // 0..65535 within slice
    const int bz  = blockIdx.y;

    float wl[11];
#pragma unroll
    for (int t = 0; t < 11; ++t) wl[t] = w11[t];

    const h4* FA = (const h4*)(fields + (size_t)bz * 10 * VOL);
    const _Float16* F2 = (const _Float16*)((const char*)FA + (size_t)8 * VOL);

    float bX[11], bY[11], bXX[11], bYY[11], bXY[11];
#pragma unroll
    for (int t = 0; t < 11; ++t) { bX[t] = 0; bY[t] = 0; bXX[t] = 0; bYY[t] = 0; bXY[t] = 0; }

    float acc = 0.f;
#pragma unroll
    for (int s = 0; s < 42; ++s) {
        const int dd = DHALF * 32 - 5 + s;          // compile-time after unroll
        const int slot = s % 11;                    // compile-time
        if (dd >= 0 && dd < 64) {                   // compile-time
            size_t idx = (size_t)dd * HW + col;
            h4 v = FA[idx];
            _Float16 vxy = F2[idx];
            bX[slot]  = (float)v[0];
            bY[slot]  = (float)v[1];
            bXX[slot] = (float)v[2];
            bYY[slot] = (float)v[3];
            bXY[slot] = (float)vxy;
        } else {
            bX[slot] = 0; bY[slot] = 0; bXX[slot] = 0; bYY[slot] = 0; bXY[slot] = 0;
        }

        if (s >= 10) {                              // compile-time; emit depth DHALF*32 + s-10
            float mX = 0, mY = 0, cXX = 0, cYY = 0, cXY = 0;
#pragma unroll
            for (int t = 0; t < 11; ++t) {
                const int j = (s + 1 + t) % 11;     // compile-time
                float wt = wl[t];
                mX  += wt * bX[j];
                mY  += wt * bY[j];
                cXX += wt * bXX[j];
                cYY += wt * bYY[j];
                cXY += wt * bXY[j];
            }
            float mx2 = mX * mX, my2 = mY * mY, mxy = mX * mY;
            float sx2 = cXX - mx2, sy2 = cYY - my2, sxy = cXY - mxy;
            float num = (2.f * mxy + C1v) * (2.f * sxy + C2v);
            float den = (mx2 + my2 + C1v) * (sx2 + sy2 + C2v);
            acc += num * __builtin_amdgcn_rcpf(den + EPSv);
        }
    }

    // reduce 256 threads -> one partial per block (deterministic)
    for (int off = 32; off; off >>= 1) acc += __shfl_down(acc, off, 64);
    __shared__ float wsum[4];
    int lane = threadIdx.x & 63, wid = threadIdx.x >> 6;
    if (lane == 0) wsum[wid] = acc;
    __syncthreads();
    if (threadIdx.x == 0) {
        float s = wsum[0] + wsum[1] + wsum[2] + wsum[3];
        partials[(size_t)(b0 + bz) * 512 + DHALF * 256 + blockIdx.x] = (double)s;
    }
}

__global__ void finalize(const double* __restrict__ partials, float* __restrict__ out, int n) {
    __shared__ double sh[256];
    double s = 0.0;
    for (int i = threadIdx.x; i < n; i += 256) s += partials[i];
    sh[threadIdx.x] = s;
    __syncthreads();
    for (int stride = 128; stride; stride >>= 1) {
        if (threadIdx.x < stride) sh[threadIdx.x] += sh[threadIdx.x + stride];
        __syncthreads();
    }
    if (threadIdx.x == 0) out[0] = 1.0f - (float)(sh[0] / (double)NTOT);
}

extern "C" void kernel_launch(void* const* d_in, const int* in_sizes, int n_in,
                              void* d_out, int out_size, void* d_ws, size_t ws_size,
                              hipStream_t stream) {
    const float* x  = (const float*)d_in[0];
    const float* y  = (const float*)d_in[1];
    const float* k3 = (const float*)d_in[2];
    float* out = (float*)d_out;

    char* ws = (char*)d_ws;
    float*   w11      = (float*)ws;
    double*  partials = (double*)(ws + 64);
    char*    fields   = ws + 16640;

    const size_t perBatch = (size_t)10 * VOL;   // packed fp16 fields per batch (bytes)
    const bool all4 = ws_size >= 16640 + 4 * perBatch;

    init_weights<<<1, 64, 0, stream>>>(k3, w11);

    if (all4) {
        blur_hw      <<<dim3(4, 16, 256), 256, 0, stream>>>(x, y, w11, fields, 0);
        dconv_ssim<0><<<dim3(256, 4),     256, 0, stream>>>(fields, w11, partials, 0);
        dconv_ssim<1><<<dim3(256, 4),     256, 0, stream>>>(fields, w11, partials, 0);
    } else {
        for (int b = 0; b < 4; ++b) {
            blur_hw      <<<dim3(4, 16, 64), 256, 0, stream>>>(x, y, w11, fields, b);
            dconv_ssim<0><<<dim3(256, 1),    256, 0, stream>>>(fields, w11, partials, b);
            dconv_ssim<1><<<dim3(256, 1),    256, 0, stream>>>(fields, w11, partials, b);
        }
    }

    finalize<<<1, 256, 0, stream>>>(partials, out, 2048);
}

// Round 17
// 137.993 us; speedup vs baseline: 1.1694x; 1.0567x over previous
//
#include <hip/hip_runtime.h>

#define HW   (256*256)        // 65536
#define VOL  (64*HW)          // 4194304 per batch volume
#define NTOT (4ull*VOL)
#define C1v  1e-4f
#define C2v  9e-4f
#define EPSv 1e-8f

typedef float    f2 __attribute__((ext_vector_type(2)));
typedef float    f4 __attribute__((ext_vector_type(4)));
typedef _Float16 h2 __attribute__((ext_vector_type(2)));
typedef _Float16 h4 __attribute__((ext_vector_type(4)));
typedef _Float16 h8 __attribute__((ext_vector_type(8)));
typedef __fp16   g2 __attribute__((ext_vector_type(2)));   // cvt_pkrtz return type

// ws layout:
// [0      .. 63]     : w[11] float (1D separable weights)
// [64     .. 16447]  : partials[2048] double
// [16640  .. ]       : packed field volumes, 10 bytes/element per batch:
//                      FA = h4{X,Y,XX,YY}[VOL] (8 B/elem), F2 = f16 XY[VOL] (2 B/elem)

__global__ void init_weights(const float* __restrict__ k3, float* __restrict__ w) {
    int i = threadIdx.x;
    if (i < 11) {
        float s = 0.f;
        for (int t = 0; t < 121; ++t) s += k3[i * 121 + t];
        w[i] = s;   // k3 is separable: row-sum = 1D weight
    }
}

// Pass 1 via MFMA banded matmuls — r15 structure + hot-line row clamp + fp16
// product staging (cvt_pkrtz + pk_mul).
//   PB[5][32][88] rows 176 B (2-way free); TT[5][64][32] aliases PB, swizzle
//   byte ^= (col&7)<<4 (wave-private); WB/AH[16][40] rows 80 B.
//   barriers: 2 (stage->Wconv reads; Wconv reads->TT writes)
// grid: (4, 16, 64*nb) x 256.
__global__ __launch_bounds__(256) void blur_hw(
    const float* __restrict__ x, const float* __restrict__ y,
    const float* __restrict__ w11, char* __restrict__ fields, int b0)
{
    __shared__ alignas(16) _Float16 PB[5 * 32 * 88];  // 28,160 B; TT (20,480 B) aliases
    __shared__ alignas(16) _Float16 WB[16][40];       //  1,280 B
    __shared__ alignas(16) _Float16 AH[16][40];       //  1,280 B -> 30,720 B (5 blk/CU)

    const int d   = blockIdx.z & 63;
    const int bz  = blockIdx.z >> 6;
    const int h0  = blockIdx.y * 16;
    const int w0  = blockIdx.x * 64;
    const int tid = threadIdx.x;

    // ---- band tables: 512 items (cols 32..39 pad, never read) ----
#pragma unroll
    for (int it = 0; it < 2; ++it) {
        int t = tid + it * 256;
        int n = t >> 5, k = t & 31;
        int i1 = k - n - 1;                 // W band (staged-col shift)
        int i2 = k - n;                     // H band
        float v1 = ((unsigned)i1 <= 10u) ? w11[min(max(i1, 0), 10)] : 0.f;
        float v2 = ((unsigned)i2 <= 10u) ? w11[min(max(i2, 0), 10)] : 0.f;
        WB[n][k] = (_Float16)v1;
        AH[n][k] = (_Float16)v2;
    }

    const float* xb = x + (size_t)(b0 + bz) * VOL + (size_t)d * HW;
    const float* yb = y + (size_t)(b0 + bz) * VOL + (size_t)d * HW;

    // ---- stage products: 32 rows x 40 col-pairs = 1280 = 5*256 exact,
    //      branchless clamped loads; garbage rows clamp INTO the tile's own
    //      rows (rmax) so they hit L1/L2 instead of fetching cold lines ----
    const int rmax = min(h0 + 20, 255);
#pragma unroll
    for (int it = 0; it < 5; ++it) {
        int p = tid + it * 256;
        int r = p / 40, j = p - r * 40;
        int gh = h0 - 5 + r;
        int gw = w0 - 6 + 2 * j;            // even
        bool ok = (r < 26) & ((unsigned)gh < 256u) & ((unsigned)gw < 256u);
        int idx = min(max(gh, 0), rmax) * 256 + min(max(gw, 0), 254);
        f2 xv = *(const f2*)&xb[idx];
        f2 yv = *(const f2*)&yb[idx];
        if (!ok) { xv = (f2){0.f, 0.f}; yv = (f2){0.f, 0.f}; }
        g2 gx = __builtin_amdgcn_cvt_pkrtz(xv[0], xv[1]);
        g2 gy = __builtin_amdgcn_cvt_pkrtz(yv[0], yv[1]);
        h2 hx = *(h2*)&gx;
        h2 hy = *(h2*)&gy;
        _Float16* pb = PB + r * 88 + j * 2;          // field stride 2816 halves
        *(h2*)(pb + 0)     = hx;
        *(h2*)(pb + 2816)  = hy;
        *(h2*)(pb + 5632)  = hx * hx;
        *(h2*)(pb + 8448)  = hy * hy;
        *(h2*)(pb + 11264) = hx * hy;
    }
    __syncthreads();   // barrier 1: staging -> W-conv reads

    const int lane = tid & 63, wid = tid >> 6;
    const int lm = lane & 15, lk = lane >> 4;
    const int col = wid * 16 + lm;                     // 0..63, wave-private block
    const int tswz = (col & 7) << 4;                   // bits 4,5 inner; bit 6 = col b0

    // ---- W-conv into registers (PB still live) ----
    h4 wres[10];
    {
        h8 bw = *(const h8*)((const char*)WB + lm * 80 + lk * 16);
        const char* Ab = (const char*)PB + lm * 176 + wid * 32 + lk * 16;
#pragma unroll
        for (int f = 0; f < 5; ++f) {
#pragma unroll
            for (int mc = 0; mc < 2; ++mc) {
                h8 a = *(const h8*)(Ab + f * 5632 + mc * 2816);
                f4 dv = __builtin_amdgcn_mfma_f32_16x16x32_f16(
                            a, bw, (f4){0.f, 0.f, 0.f, 0.f}, 0, 0, 0);
                wres[f * 2 + mc] = (h4){(_Float16)dv[0], (_Float16)dv[1],
                                        (_Float16)dv[2], (_Float16)dv[3]};
            }
        }
    }
    __syncthreads();   // barrier 2: all PB reads done -> safe to overwrite with TT

    // ---- write swizzled TT (aliased over PB); cols wave-private ----
    {
        char* T0 = (char*)PB;
#pragma unroll
        for (int f = 0; f < 5; ++f) {
#pragma unroll
            for (int mc = 0; mc < 2; ++mc) {
                char* dst = T0 + ((col * 64 + mc * 32 + lk * 8) ^ tswz) + f * 4096;
                *(h4*)dst = wres[f * 2 + mc];
            }
        }
    }
    // no barrier: wave reads exactly the TT cols it wrote (lgkmcnt ordered)

    // ---- H-conv: wave = N-chunk; 5 fields, fused FA(h4) + F2 stores ----
    {
        h8 ah = *(const h8*)((const char*)AH + lm * 80 + lk * 16);
        const char* Tb = (const char*)PB + ((col * 64 + lk * 16) ^ tswz);
        f4 d0 = __builtin_amdgcn_mfma_f32_16x16x32_f16(ah, *(const h8*)(Tb + 0),
                    (f4){0.f,0.f,0.f,0.f}, 0, 0, 0);
        f4 d1 = __builtin_amdgcn_mfma_f32_16x16x32_f16(ah, *(const h8*)(Tb + 4096),
                    (f4){0.f,0.f,0.f,0.f}, 0, 0, 0);
        f4 d2 = __builtin_amdgcn_mfma_f32_16x16x32_f16(ah, *(const h8*)(Tb + 8192),
                    (f4){0.f,0.f,0.f,0.f}, 0, 0, 0);
        f4 d3 = __builtin_amdgcn_mfma_f32_16x16x32_f16(ah, *(const h8*)(Tb + 12288),
                    (f4){0.f,0.f,0.f,0.f}, 0, 0, 0);
        f4 d4 = __builtin_amdgcn_mfma_f32_16x16x32_f16(ah, *(const h8*)(Tb + 16384),
                    (f4){0.f,0.f,0.f,0.f}, 0, 0, 0);

        h4* FA = (h4*)(fields + (size_t)bz * 10 * VOL);
        _Float16* F2 = (_Float16*)((char*)FA + (size_t)8 * VOL);

        const int gcol = w0 + col;
#pragma unroll
        for (int rg = 0; rg < 4; ++rg) {
            int row = lk * 4 + rg;
            size_t oi = (size_t)d * HW + (size_t)(h0 + row) * 256 + gcol;
            FA[oi] = (h4){(_Float16)d0[rg], (_Float16)d1[rg],
                          (_Float16)d2[rg], (_Float16)d3[rg]};
            F2[oi] = (_Float16)d4[rg];
        }
    }
}

// Pass 2: D-conv via scalar fp32 register rings, fused h4 field loads.
// DHALF compile-time so ALL guards fold; grid: (256, nb) x 256.
template<int DHALF>
__global__ __launch_bounds__(256) void dconv_ssim(
    const char* __restrict__ fields, const float* __restrict__ w11,
    double* __restrict__ partials, int b0)
{
    const int col = blockIdx.x * 256 + threadIdx.x;  // 0..65535 within slice
    const int bz  = blockIdx.y;

    float wl[11];
#pragma unroll
    for (int t = 0; t < 11; ++t) wl[t] = w11[t];

    const h4* FA = (const h4*)(fields + (size_t)bz * 10 * VOL);
    const _Float16* F2 = (const _Float16*)((const char*)FA + (size_t)8 * VOL);

    float bX[11], bY[11], bXX[11], bYY[11], bXY[11];
#pragma unroll
    for (int t = 0; t < 11; ++t) { bX[t] = 0; bY[t] = 0; bXX[t] = 0; bYY[t] = 0; bXY[t] = 0; }

    float acc = 0.f;
#pragma unroll
    for (int s = 0; s < 42; ++s) {
        const int dd = DHALF * 32 - 5 + s;          // compile-time after unroll
        const int slot = s % 11;                    // compile-time
        if (dd >= 0 && dd < 64) {                   // compile-time
            size_t idx = (size_t)dd * HW + col;
            h4 v = FA[idx];
            _Float16 vxy = F2[idx];
            bX[slot]  = (float)v[0];
            bY[slot]  = (float)v[1];
            bXX[slot] = (float)v[2];
            bYY[slot] = (float)v[3];
            bXY[slot] = (float)vxy;
        } else {
            bX[slot] = 0; bY[slot] = 0; bXX[slot] = 0; bYY[slot] = 0; bXY[slot] = 0;
        }

        if (s >= 10) {                              // compile-time; emit depth DHALF*32 + s-10
            float mX = 0, mY = 0, cXX = 0, cYY = 0, cXY = 0;
#pragma unroll
            for (int t = 0; t < 11; ++t) {
                const int j = (s + 1 + t) % 11;     // compile-time
                float wt = wl[t];
                mX  += wt * bX[j];
                mY  += wt * bY[j];
                cXX += wt * bXX[j];
                cYY += wt * bYY[j];
                cXY += wt * bXY[j];
            }
            float mx2 = mX * mX, my2 = mY * mY, mxy = mX * mY;
            float sx2 = cXX - mx2, sy2 = cYY - my2, sxy = cXY - mxy;
            float num = (2.f * mxy + C1v) * (2.f * sxy + C2v);
            float den = (mx2 + my2 + C1v) * (sx2 + sy2 + C2v);
            acc += num * __builtin_amdgcn_rcpf(den + EPSv);
        }
    }

    // reduce 256 threads -> one partial per block (deterministic)
    for (int off = 32; off; off >>= 1) acc += __shfl_down(acc, off, 64);
    __shared__ float wsum[4];
    int lane = threadIdx.x & 63, wid = threadIdx.x >> 6;
    if (lane == 0) wsum[wid] = acc;
    __syncthreads();
    if (threadIdx.x == 0) {
        float s = wsum[0] + wsum[1] + wsum[2] + wsum[3];
        partials[(size_t)(b0 + bz) * 512 + DHALF * 256 + blockIdx.x] = (double)s;
    }
}

__global__ void finalize(const double* __restrict__ partials, float* __restrict__ out, int n) {
    __shared__ double sh[256];
    double s = 0.0;
    for (int i = threadIdx.x; i < n; i += 256) s += partials[i];
    sh[threadIdx.x] = s;
    __syncthreads();
    for (int stride = 128; stride; stride >>= 1) {
        if (threadIdx.x < stride) sh[threadIdx.x] += sh[threadIdx.x + stride];
        __syncthreads();
    }
    if (threadIdx.x == 0) out[0] = 1.0f - (float)(sh[0] / (double)NTOT);
}

extern "C" void kernel_launch(void* const* d_in, const int* in_sizes, int n_in,
                              void* d_out, int out_size, void* d_ws, size_t ws_size,
                              hipStream_t stream) {
    const float* x  = (const float*)d_in[0];
    const float* y  = (const float*)d_in[1];
    const float* k3 = (const float*)d_in[2];
    float* out = (float*)d_out;

    char* ws = (char*)d_ws;
    float*   w11      = (float*)ws;
    double*  partials = (double*)(ws + 64);
    char*    fields   = ws + 16640;

    const size_t perBatch = (size_t)10 * VOL;   // packed fp16 fields per batch (bytes)
    const bool all4 = ws_size >= 16640 + 4 * perBatch;

    init_weights<<<1, 64, 0, stream>>>(k3, w11);

    if (all4) {
        blur_hw      <<<dim3(4, 16, 256), 256, 0, stream>>>(x, y, w11, fields, 0);
        dconv_ssim<0><<<dim3(256, 4),     256, 0, stream>>>(fields, w11, partials, 0);
        dconv_ssim<1><<<dim3(256, 4),     256, 0, stream>>>(fields, w11, partials, 0);
    } else {
        for (int b = 0; b < 4; ++b) {
            blur_hw      <<<dim3(4, 16, 64), 256, 0, stream>>>(x, y, w11, fields, b);
            dconv_ssim<0><<<dim3(256, 1),    256, 0, stream>>>(fields, w11, partials, b);
            dconv_ssim<1><<<dim3(256, 1),    256, 0, stream>>>(fields, w11, partials, b);
        }
    }

    finalize<<<1, 256, 0, stream>>>(partials, out, 2048);
}